// Round 2
// baseline (176.384 us; speedup 1.0000x reference)
//
#include <hip/hip_runtime.h>
#include <hip/hip_bf16.h>
#include <stdint.h>

// Problem: B=16, C=256, H=W=32 -> S=1024, NH=4, DK=64, N_qkv=768
typedef float f32x4 __attribute__((ext_vector_type(4)));
typedef __bf16 bf16x8 __attribute__((ext_vector_type(8)));
typedef unsigned short u16x8 __attribute__((ext_vector_type(8)));

#define MFMA16(a, b, c) __builtin_amdgcn_mfma_f32_16x16x32_bf16(a, b, c, 0, 0, 0)

// SCALE * log2(e): fold into Q so softmax can use exp2 (v_exp_f32) directly.
#define QSCALE 0.18033688011112042f

static __device__ __forceinline__ unsigned short f2bf(float f) {
    uint32_t u = __builtin_bit_cast(uint32_t, f);
    u = u + 0x7FFFu + ((u >> 16) & 1u);
    return (unsigned short)(u >> 16);
}

static __device__ __forceinline__ bf16x8 ldb8(const unsigned short* p) {
    return __builtin_bit_cast(bf16x8, *reinterpret_cast<const u16x8*>(p));
}

// async global->LDS, 16B per lane; LDS dest is wave-uniform base + lane*16
static __device__ __forceinline__ void gload16(const void* g, void* l) {
    __builtin_amdgcn_global_load_lds(
        (const __attribute__((address_space(1))) void*)g,
        (__attribute__((address_space(3))) void*)l,
        16, 0, 0);
}

// ---------------- batched fp32 [b][R][Cc] -> bf16 [b][Cc][R] tile transpose ----------------
__global__ __launch_bounds__(256) void k_t(const float* __restrict__ src,
                                           unsigned short* __restrict__ dst,
                                           int R, int Cc, int nRT, int nCT) {
    int bid = blockIdx.x;
    int ct = bid % nCT;
    int rt = (bid / nCT) % nRT;
    int b  = bid / (nCT * nRT);
    int t = threadIdx.x;
    __shared__ __align__(16) unsigned short tile[64][72];
    int tr = t >> 2, tc = (t & 3) * 16;
    const float* sp = src + ((size_t)(b * R + rt * 64 + tr)) * Cc + ct * 64 + tc;
#pragma unroll
    for (int j = 0; j < 4; ++j) {
        float4 v = reinterpret_cast<const float4*>(sp)[j];
        ushort4 hv; hv.x = f2bf(v.x); hv.y = f2bf(v.y); hv.z = f2bf(v.z); hv.w = f2bf(v.w);
        *reinterpret_cast<ushort4*>(&tile[tr][tc + 4 * j]) = hv;
    }
    __syncthreads();
    int c = t >> 2, rs = (t & 3) * 16;
    u16x8 o0, o1;
#pragma unroll
    for (int z = 0; z < 8; ++z) o0[z] = tile[rs + z][c];
#pragma unroll
    for (int z = 0; z < 8; ++z) o1[z] = tile[rs + 8 + z][c];
    unsigned short* dp = dst + ((size_t)b * Cc + ct * 64 + c) * R + rt * 64 + rs;
    *reinterpret_cast<u16x8*>(dp) = o0;
    *reinterpret_cast<u16x8*>(dp + 8) = o1;
}

// ---------------- QKV GEMM: qkv[m][768] = xT[m][256] @ wT^T + bias (Q pre-scaled) ----------------
__global__ __launch_bounds__(256) void k_gemm_qkv(const unsigned short* __restrict__ xT,
                                                  const unsigned short* __restrict__ wT,
                                                  const float* __restrict__ bias,
                                                  unsigned short* __restrict__ qkv) {
    int bid = blockIdx.x;            // 128 mtiles * 6 ntiles
    int mt = bid / 6, nt = bid - mt * 6;
    int tid = threadIdx.x;
    int w = tid >> 6, l = tid & 63;
    int l15 = l & 15, lg = l >> 4;
    int wm = (w >> 1) * 64, wn = (w & 1) * 64;

    __shared__ __align__(16) unsigned short Al[128 * 32];
    __shared__ __align__(16) unsigned short Bl[128 * 32];

    f32x4 acc[4][4] = {};

    const char* Agb = (const char*)xT + (size_t)mt * 128 * 512;
    const char* Bgb = (const char*)wT + (size_t)nt * 128 * 512;
    int r0 = w * 32;                        // wave stages rows r0..r0+31 of A and B
    size_t lrow_off = (size_t)(r0 + (l >> 2)) * 512 + (l & 3) * 16;

    for (int kt = 0; kt < 256; kt += 32) {
        __syncthreads();
        const char* ag = Agb + lrow_off + kt * 2;
        const char* bg = Bgb + lrow_off + kt * 2;
        gload16(ag,             (char*)Al + r0 * 64);
        gload16(ag + 16 * 512,  (char*)Al + r0 * 64 + 1024);
        gload16(bg,             (char*)Bl + r0 * 64);
        gload16(bg + 16 * 512,  (char*)Bl + r0 * 64 + 1024);
        __syncthreads();
        bf16x8 af[4], bfr[4];
#pragma unroll
        for (int mi = 0; mi < 4; ++mi)
            af[mi] = ldb8(&Al[(wm + mi * 16 + l15) * 32 + lg * 8]);
#pragma unroll
        for (int ni = 0; ni < 4; ++ni)
            bfr[ni] = ldb8(&Bl[(wn + ni * 16 + l15) * 32 + lg * 8]);
#pragma unroll
        for (int mi = 0; mi < 4; ++mi)
#pragma unroll
            for (int ni = 0; ni < 4; ++ni)
                acc[mi][ni] = MFMA16(af[mi], bfr[ni], acc[mi][ni]);
    }

#pragma unroll
    for (int ni = 0; ni < 4; ++ni) {
        int n = nt * 128 + wn + ni * 16 + l15;
        float bz = bias[n];
        float qs = ((n % 192) < 64) ? QSCALE : 1.0f;   // scale Q columns (incl. bias)
#pragma unroll
        for (int mi = 0; mi < 4; ++mi) {
            int mg = mt * 128 + wm + mi * 16 + lg * 4;
            unsigned short* qp = qkv + (size_t)mg * 768 + n;
#pragma unroll
            for (int r = 0; r < 4; ++r)
                qp[(size_t)r * 768] = f2bf((acc[mi][ni][r] + bz) * qs);
    }
    }
}

// ---------------- V transpose: qkv V-part [s][d] -> vT[bh][d][s] ----------------
__global__ __launch_bounds__(256) void k_vt(const unsigned short* __restrict__ qkv,
                                            unsigned short* __restrict__ vT) {
    int bid = blockIdx.x;            // (b*4+h)*16 + jt
    int jt = bid & 15;
    int bh = bid >> 4;
    int h = bh & 3;
    size_t bb = (size_t)(bh >> 2) * 1024;
    int t = threadIdx.x;
    __shared__ __align__(16) unsigned short tile[64][72];
    int jr = t >> 2, ds = (t & 3) * 16;
    const unsigned short* sp = qkv + (bb + jt * 64 + jr) * 768 + h * 192 + 128 + ds;
    *reinterpret_cast<u16x8*>(&tile[jr][ds])     = *reinterpret_cast<const u16x8*>(sp);
    *reinterpret_cast<u16x8*>(&tile[jr][ds + 8]) = *reinterpret_cast<const u16x8*>(sp + 8);
    __syncthreads();
    int d = t >> 2, js = (t & 3) * 16;
    u16x8 o0, o1;
#pragma unroll
    for (int z = 0; z < 8; ++z) o0[z] = tile[js + z][d];
#pragma unroll
    for (int z = 0; z < 8; ++z) o1[z] = tile[js + 8 + z][d];
    unsigned short* dp = vT + ((size_t)bh * 64 + d) * 1024 + jt * 64 + js;
    *reinterpret_cast<u16x8*>(dp) = o0;
    *reinterpret_cast<u16x8*>(dp + 8) = o1;
}

// ---------------- flash attention: QBLK=64, 4 waves x 16 rows, KV tile 64 ----------------
__global__ __launch_bounds__(256) void k_attn(const unsigned short* __restrict__ qkv,
                                              const unsigned short* __restrict__ vT,
                                              unsigned short* __restrict__ ao) {
    int bid = blockIdx.x;            // b(16) * h(4) * qt(16) = 1024
    int qt = bid & 15;
    int h  = (bid >> 4) & 3;
    int b  = bid >> 6;
    int tid = threadIdx.x;
    int w = tid >> 6, l = tid & 63;
    int l15 = l & 15, lg = l >> 4;

    __shared__ __align__(16) unsigned short Kl[64][72];
    __shared__ __align__(16) unsigned short Vt[64][72];
    __shared__ __align__(16) unsigned short Pl[4][16][72];

    const size_t bb = (size_t)b * 1024;
    const unsigned short* qbase = qkv + bb * 768 + h * 192;

    bf16x8 qf[2];
    int qrow = qt * 64 + w * 16 + l15;
#pragma unroll
    for (int kf = 0; kf < 2; ++kf)
        qf[kf] = ldb8(qbase + (size_t)qrow * 768 + kf * 32 + lg * 8);

    f32x4 mrow, lrow, oacc[4];
#pragma unroll
    for (int r = 0; r < 4; ++r) { mrow[r] = -1e30f; lrow[r] = 0.0f; }
#pragma unroll
    for (int df = 0; df < 4; ++df)
#pragma unroll
        for (int r = 0; r < 4; ++r) oacc[df][r] = 0.0f;

    int rr = tid >> 2;               // 0..63: K row j / V row d
    int cs = (tid & 3) << 4;         // 16-elem segment
    const unsigned short* kg = qkv + bb * 768 + h * 192 + 64 + (size_t)rr * 768 + cs;
    const unsigned short* vg = vT + ((size_t)(b * 4 + h) * 64 + rr) * 1024 + cs;

    for (int jt = 0; jt < 1024; jt += 64) {
        __syncthreads();
        {
            const unsigned short* kp = kg + (size_t)jt * 768;
            u16x8 k0 = *reinterpret_cast<const u16x8*>(kp);
            u16x8 k1 = *reinterpret_cast<const u16x8*>(kp + 8);
            *reinterpret_cast<u16x8*>(&Kl[rr][cs]) = k0;
            *reinterpret_cast<u16x8*>(&Kl[rr][cs + 8]) = k1;
            const unsigned short* vp = vg + jt;
            u16x8 v0 = *reinterpret_cast<const u16x8*>(vp);
            u16x8 v1 = *reinterpret_cast<const u16x8*>(vp + 8);
            *reinterpret_cast<u16x8*>(&Vt[rr][cs]) = v0;
            *reinterpret_cast<u16x8*>(&Vt[rr][cs + 8]) = v1;
        }
        __syncthreads();

        // S = Q K^T   (Q pre-scaled by SCALE*log2e)
        f32x4 sa[4] = {};
#pragma unroll
        for (int ni = 0; ni < 4; ++ni) {
            bf16x8 kb0 = ldb8(&Kl[ni * 16 + l15][lg * 8]);
            bf16x8 kb1 = ldb8(&Kl[ni * 16 + l15][32 + lg * 8]);
            sa[ni] = MFMA16(qf[0], kb0, sa[ni]);
            sa[ni] = MFMA16(qf[1], kb1, sa[ni]);
        }

        // online softmax in exp2 domain
        f32x4 p;
#pragma unroll
        for (int r = 0; r < 4; ++r)
            p[r] = fmaxf(fmaxf(sa[0][r], sa[1][r]), fmaxf(sa[2][r], sa[3][r]));
#pragma unroll
        for (int d = 1; d < 16; d <<= 1)
#pragma unroll
            for (int r = 0; r < 4; ++r) p[r] = fmaxf(p[r], __shfl_xor(p[r], d));
        f32x4 ef;
#pragma unroll
        for (int r = 0; r < 4; ++r) {
            float mn = fmaxf(mrow[r], p[r]);
            ef[r] = __builtin_amdgcn_exp2f(mrow[r] - mn);
            mrow[r] = mn;
        }
        f32x4 rs;
#pragma unroll
        for (int r = 0; r < 4; ++r) rs[r] = 0.0f;
#pragma unroll
        for (int ni = 0; ni < 4; ++ni)
#pragma unroll
            for (int r = 0; r < 4; ++r) {
                float pv = __builtin_amdgcn_exp2f(sa[ni][r] - mrow[r]);
                sa[ni][r] = pv;
                rs[r] += pv;
            }
#pragma unroll
        for (int ni = 0; ni < 4; ++ni)
#pragma unroll
            for (int r = 0; r < 4; ++r)
                Pl[w][lg * 4 + r][ni * 16 + l15] = f2bf(sa[ni][r]);
#pragma unroll
        for (int d = 1; d < 16; d <<= 1)
#pragma unroll
            for (int r = 0; r < 4; ++r) rs[r] += __shfl_xor(rs[r], d);
#pragma unroll
        for (int r = 0; r < 4; ++r) lrow[r] = lrow[r] * ef[r] + rs[r];
#pragma unroll
        for (int df = 0; df < 4; ++df)
#pragma unroll
            for (int r = 0; r < 4; ++r) oacc[df][r] *= ef[r];

        // O += P @ V
#pragma unroll
        for (int kf = 0; kf < 2; ++kf) {
            bf16x8 pa = ldb8(&Pl[w][l15][kf * 32 + lg * 8]);
#pragma unroll
            for (int df = 0; df < 4; ++df) {
                bf16x8 vb = ldb8(&Vt[df * 16 + l15][kf * 32 + lg * 8]);
                oacc[df] = MFMA16(pa, vb, oacc[df]);
            }
        }
    }

    f32x4 inv;
#pragma unroll
    for (int r = 0; r < 4; ++r) inv[r] = 1.0f / lrow[r];
#pragma unroll
    for (int df = 0; df < 4; ++df)
#pragma unroll
        for (int r = 0; r < 4; ++r) {
            int i = qt * 64 + w * 16 + lg * 4 + r;
            int d = df * 16 + l15;
            ao[(bb + i) * 256 + h * 64 + d] = f2bf(oacc[df][r] * inv[r]);
        }
}

// ---------------- out GEMM 64x64 tiles + bias + residual, transposed fp32 store ----------------
__global__ __launch_bounds__(256) void k_gemm_out(const unsigned short* __restrict__ aoin,
                                                  const unsigned short* __restrict__ wT,
                                                  const float* __restrict__ bias,
                                                  const float* __restrict__ x,
                                                  float* __restrict__ out) {
    int bid = blockIdx.x;            // 256 mtiles * 4 ntiles
    int mt = bid >> 2, nt = bid & 3;
    int tid = threadIdx.x;
    int w = tid >> 6, l = tid & 63;
    int l15 = l & 15, lg = l >> 4;
    int wm = (w >> 1) * 32, wn = (w & 1) * 32;

    __shared__ __align__(16) unsigned short Al[64 * 32];
    __shared__ __align__(16) unsigned short Bl[64 * 32];

    f32x4 acc[2][2] = {};

    const char* Agb = (const char*)aoin + (size_t)mt * 64 * 512;
    const char* Bgb = (const char*)wT + (size_t)nt * 64 * 512;
    int r0 = w * 16;
    size_t lrow_off = (size_t)(r0 + (l >> 2)) * 512 + (l & 3) * 16;

    for (int kt = 0; kt < 256; kt += 32) {
        __syncthreads();
        gload16(Agb + lrow_off + kt * 2, (char*)Al + r0 * 64);
        gload16(Bgb + lrow_off + kt * 2, (char*)Bl + r0 * 64);
        __syncthreads();
        bf16x8 af[2], bfr[2];
#pragma unroll
        for (int mi = 0; mi < 2; ++mi)
            af[mi] = ldb8(&Al[(wm + mi * 16 + l15) * 32 + lg * 8]);
#pragma unroll
        for (int ni = 0; ni < 2; ++ni)
            bfr[ni] = ldb8(&Bl[(wn + ni * 16 + l15) * 32 + lg * 8]);
#pragma unroll
        for (int mi = 0; mi < 2; ++mi)
#pragma unroll
            for (int ni = 0; ni < 2; ++ni)
                acc[mi][ni] = MFMA16(af[mi], bfr[ni], acc[mi][ni]);
    }

#pragma unroll
    for (int ni = 0; ni < 2; ++ni) {
        int n = nt * 64 + wn + ni * 16 + l15;
        float bz = bias[n];
#pragma unroll
        for (int mi = 0; mi < 2; ++mi) {
            int mg = mt * 64 + wm + mi * 16 + lg * 4;
            int bI = mg >> 10, i = mg & 1023;
            size_t o = (((size_t)(bI * 256 + n)) << 10) + i;
            float4 xr = *reinterpret_cast<const float4*>(x + o);
            float4 res;
            res.x = acc[mi][ni][0] + bz + xr.x;
            res.y = acc[mi][ni][1] + bz + xr.y;
            res.z = acc[mi][ni][2] + bz + xr.z;
            res.w = acc[mi][ni][3] + bz + xr.w;
            *reinterpret_cast<float4*>(out + o) = res;
        }
    }
}

extern "C" void kernel_launch(void* const* d_in, const int* in_sizes, int n_in,
                              void* d_out, int out_size, void* d_ws, size_t ws_size,
                              hipStream_t stream) {
    const float* x      = (const float*)d_in[0];
    const float* w_proj = (const float*)d_in[1];
    const float* b_proj = (const float*)d_in[2];
    const float* w_out  = (const float*)d_in[3];
    const float* b_out  = (const float*)d_in[4];
    float* out = (float*)d_out;

    char* ws = (char*)d_ws;
    unsigned short* xT     = (unsigned short*)(ws);                 //  8,388,608 B (reused as vT)
    unsigned short* wprojT = (unsigned short*)(ws + 8388608);       //    393,216 B
    unsigned short* woutT  = (unsigned short*)(ws + 8781824);       //    131,072 B
    unsigned short* qkv    = (unsigned short*)(ws + 8912896);       // 25,165,824 B
    unsigned short* ao     = (unsigned short*)(ws + 34078720);      //  8,388,608 B
    unsigned short* vT     = xT;     // xT is dead after k_gemm_qkv

    k_t<<<1024, 256, 0, stream>>>(x, xT, 256, 1024, 4, 16);
    k_t<<<48,   256, 0, stream>>>(w_proj, wprojT, 256, 768, 4, 12);
    k_t<<<16,   256, 0, stream>>>(w_out, woutT, 256, 256, 4, 4);
    k_gemm_qkv<<<768, 256, 0, stream>>>(xT, wprojT, b_proj, qkv);
    k_vt<<<1024, 256, 0, stream>>>(qkv, vT);
    k_attn<<<1024, 256, 0, stream>>>(qkv, vT, ao);
    k_gemm_out<<<1024, 256, 0, stream>>>(ao, woutT, b_out, x, out);
}

// Round 6
// 146.771 us; speedup vs baseline: 1.2018x; 1.2018x over previous
//
#include <hip/hip_runtime.h>
#include <hip/hip_bf16.h>
#include <stdint.h>

// Problem: B=16, C=256, H=W=32 -> S=1024, NH=4, DK=64, N_qkv=768
typedef float f32x4 __attribute__((ext_vector_type(4)));
typedef float f32x16 __attribute__((ext_vector_type(16)));
typedef __bf16 bf16x8 __attribute__((ext_vector_type(8)));
typedef unsigned short u16x8 __attribute__((ext_vector_type(8)));
typedef int i32x4 __attribute__((ext_vector_type(4)));

#define MFMA16(a, b, c) __builtin_amdgcn_mfma_f32_16x16x32_bf16(a, b, c, 0, 0, 0)
#define MFMA32(a, b, c) __builtin_amdgcn_mfma_f32_32x32x16_bf16(a, b, c, 0, 0, 0)

// SCALE * log2(e): folded into Q so softmax runs in exp2 domain.
#define QSCALE 0.18033688011112042f

static __device__ __forceinline__ unsigned short f2bf(float f) {
    uint32_t u = __builtin_bit_cast(uint32_t, f);
    u = u + 0x7FFFu + ((u >> 16) & 1u);
    return (unsigned short)(u >> 16);
}

static __device__ __forceinline__ bf16x8 ldb8(const unsigned short* p) {
    return __builtin_bit_cast(bf16x8, *reinterpret_cast<const u16x8*>(p));
}

// async global->LDS, 16B/lane; LDS dest = wave-uniform base + lane*16
static __device__ __forceinline__ void gload16(const void* g, void* l) {
    __builtin_amdgcn_global_load_lds(
        (const __attribute__((address_space(1))) void*)g,
        (__attribute__((address_space(3))) void*)l,
        16, 0, 0);
}

// ---------------- merged transposes: fp32 [b][R][Cc] -> bf16 [b][Cc][R] ----------------
__global__ __launch_bounds__(256) void k_tall(const float* __restrict__ x,
                                              const float* __restrict__ wp,
                                              const float* __restrict__ wo,
                                              unsigned short* __restrict__ xT,
                                              unsigned short* __restrict__ wpT,
                                              unsigned short* __restrict__ woT) {
    int bid = blockIdx.x;
    const float* src; unsigned short* dst; int Cc, nCT; int lb;
    if (bid < 1024)      { src = x;  dst = xT;  Cc = 1024; nCT = 16; lb = bid; }
    else if (bid < 1072) { src = wp; dst = wpT; Cc = 768;  nCT = 12; lb = bid - 1024; }
    else                 { src = wo; dst = woT; Cc = 256;  nCT = 4;  lb = bid - 1072; }
    int R = 256, nRT = 4;
    int ct = lb % nCT;
    int rt = (lb / nCT) % nRT;
    int b  = lb / (nCT * nRT);
    int t = threadIdx.x;
    __shared__ __align__(16) unsigned short tile[64][72];
    int tr = t >> 2, tc = (t & 3) * 16;
    const float* sp = src + ((size_t)(b * R + rt * 64 + tr)) * Cc + ct * 64 + tc;
#pragma unroll
    for (int j = 0; j < 4; ++j) {
        float4 v = reinterpret_cast<const float4*>(sp)[j];
        ushort4 hv; hv.x = f2bf(v.x); hv.y = f2bf(v.y); hv.z = f2bf(v.z); hv.w = f2bf(v.w);
        *reinterpret_cast<ushort4*>(&tile[tr][tc + 4 * j]) = hv;
    }
    __syncthreads();
    int c = t >> 2, rs = (t & 3) * 16;
    u16x8 o0, o1;
#pragma unroll
    for (int z = 0; z < 8; ++z) o0[z] = tile[rs + z][c];
#pragma unroll
    for (int z = 0; z < 8; ++z) o1[z] = tile[rs + 8 + z][c];
    unsigned short* dp = dst + ((size_t)b * Cc + ct * 64 + c) * R + rt * 64 + rs;
    *reinterpret_cast<u16x8*>(dp) = o0;
    *reinterpret_cast<u16x8*>(dp + 8) = o1;
}

// ---------------- QKV GEMM: qkv[m][768] = xT[m][256] @ wT^T + bias (Q pre-scaled) ----------------
__global__ __launch_bounds__(256) void k_gemm_qkv(const unsigned short* __restrict__ xT,
                                                  const unsigned short* __restrict__ wT,
                                                  const float* __restrict__ bias,
                                                  unsigned short* __restrict__ qkv) {
    int bid = blockIdx.x;            // 128 mtiles * 6 ntiles
    int mt = bid / 6, nt = bid - mt * 6;
    int tid = threadIdx.x;
    int w = tid >> 6, l = tid & 63;
    int l15 = l & 15, lg = l >> 4;
    int wm = (w >> 1) * 64, wn = (w & 1) * 64;

    __shared__ __align__(16) unsigned short Al[128 * 32];
    __shared__ __align__(16) unsigned short Bl[128 * 32];

    f32x4 acc[4][4] = {};

    const char* Agb = (const char*)xT + (size_t)mt * 128 * 512;
    const char* Bgb = (const char*)wT + (size_t)nt * 128 * 512;
    int r0 = w * 32;
    size_t lrow_off = (size_t)(r0 + (l >> 2)) * 512 + (l & 3) * 16;

    for (int kt = 0; kt < 256; kt += 32) {
        __syncthreads();
        const char* ag = Agb + lrow_off + kt * 2;
        const char* bg = Bgb + lrow_off + kt * 2;
        gload16(ag,             (char*)Al + r0 * 64);
        gload16(ag + 16 * 512,  (char*)Al + r0 * 64 + 1024);
        gload16(bg,             (char*)Bl + r0 * 64);
        gload16(bg + 16 * 512,  (char*)Bl + r0 * 64 + 1024);
        __syncthreads();
        bf16x8 af[4], bfr[4];
#pragma unroll
        for (int mi = 0; mi < 4; ++mi)
            af[mi] = ldb8(&Al[(wm + mi * 16 + l15) * 32 + lg * 8]);
#pragma unroll
        for (int ni = 0; ni < 4; ++ni)
            bfr[ni] = ldb8(&Bl[(wn + ni * 16 + l15) * 32 + lg * 8]);
#pragma unroll
        for (int mi = 0; mi < 4; ++mi)
#pragma unroll
            for (int ni = 0; ni < 4; ++ni)
                acc[mi][ni] = MFMA16(af[mi], bfr[ni], acc[mi][ni]);
    }

#pragma unroll
    for (int ni = 0; ni < 4; ++ni) {
        int n = nt * 128 + wn + ni * 16 + l15;
        float bz = bias[n];
        float qs = ((n % 192) < 64) ? QSCALE : 1.0f;   // scale Q columns (incl. bias)
#pragma unroll
        for (int mi = 0; mi < 4; ++mi) {
            int mg = mt * 128 + wm + mi * 16 + lg * 4;
            unsigned short* qp = qkv + (size_t)mg * 768 + n;
#pragma unroll
            for (int r = 0; r < 4; ++r)
                qp[(size_t)r * 768] = f2bf((acc[mi][ni][r] + bz) * qs);
        }
    }
}

// ---------------- V transpose: qkv V-part [s][d] -> vT[bh][d][s] ----------------
__global__ __launch_bounds__(256) void k_vt(const unsigned short* __restrict__ qkv,
                                            unsigned short* __restrict__ vT) {
    int bid = blockIdx.x;            // (b*4+h)*16 + jt
    int jt = bid & 15;
    int bh = bid >> 4;
    int h = bh & 3;
    size_t bb = (size_t)(bh >> 2) * 1024;
    int t = threadIdx.x;
    __shared__ __align__(16) unsigned short tile[64][72];
    int jr = t >> 2, ds = (t & 3) * 16;
    const unsigned short* sp = qkv + (bb + jt * 64 + jr) * 768 + h * 192 + 128 + ds;
    *reinterpret_cast<u16x8*>(&tile[jr][ds])     = *reinterpret_cast<const u16x8*>(sp);
    *reinterpret_cast<u16x8*>(&tile[jr][ds + 8]) = *reinterpret_cast<const u16x8*>(sp + 8);
    __syncthreads();
    int d = t >> 2, js = (t & 3) * 16;
    u16x8 o0, o1;
#pragma unroll
    for (int z = 0; z < 8; ++z) o0[z] = tile[js + z][d];
#pragma unroll
    for (int z = 0; z < 8; ++z) o1[z] = tile[js + 8 + z][d];
    unsigned short* dp = vT + ((size_t)bh * 64 + d) * 1024 + jt * 64 + js;
    *reinterpret_cast<u16x8*>(dp) = o0;
    *reinterpret_cast<u16x8*>(dp + 8) = o1;
}

// Pack 8 exp'd P-values (j-group) into an A-fragment (4 u32) with the
// cross-half exchange: reg0=(j0,j1) reg1=(j2,j3) reg2=(j4,j5) reg3=(j6,j7)
// per-half, exchanging halves via one shfl_xor(32) per pair (T12 pattern).
#define PACKJK(SV, R, OUT) do { \
    int pa_, pb_, pc_, pd_; \
    asm("v_cvt_pk_bf16_f32 %0, %1, %2" : "=v"(pa_) : "v"(SV[R + 0]), "v"(SV[R + 1])); \
    asm("v_cvt_pk_bf16_f32 %0, %1, %2" : "=v"(pb_) : "v"(SV[R + 2]), "v"(SV[R + 3])); \
    asm("v_cvt_pk_bf16_f32 %0, %1, %2" : "=v"(pc_) : "v"(SV[R + 4]), "v"(SV[R + 5])); \
    asm("v_cvt_pk_bf16_f32 %0, %1, %2" : "=v"(pd_) : "v"(SV[R + 6]), "v"(SV[R + 7])); \
    int pu_ = hi ? pa_ : pc_;  int psu_ = __shfl_xor(pu_, 32); \
    int pv_ = hi ? pb_ : pd_;  int psv_ = __shfl_xor(pv_, 32); \
    i32x4 pri_ = { hi ? psu_ : pa_, hi ? psv_ : pb_, hi ? pc_ : psu_, hi ? pd_ : psv_ }; \
    OUT = __builtin_bit_cast(bf16x8, pri_); \
} while (0)

// ---------------- flash attention: swapped QK^T, 32x32x16 MFMA, in-reg softmax ----------------
// 2 waves x 32 q-rows per block; KV tile 64; K/V in XOR-swizzled LDS via pre-swizzled
// global source + global_load_lds (rule #21).
__global__ __launch_bounds__(128) void k_attn(const unsigned short* __restrict__ qkv,
                                              const unsigned short* __restrict__ vT,
                                              unsigned short* __restrict__ ao) {
    int bid = blockIdx.x;            // b(16) * h(4) * qt(16) = 1024
    int qt = bid & 15;
    int h  = (bid >> 4) & 3;
    int b  = bid >> 6;
    int tid = threadIdx.x;
    int w = tid >> 6;                // wave 0/1
    int l = tid & 63;
    int l31 = l & 31;
    int hi = l >> 5;                 // half-wave
    int x7 = l & 7;

    __shared__ __align__(16) unsigned short Kl[64 * 64];
    __shared__ __align__(16) unsigned short Vl[64 * 64];

    const size_t bb = (size_t)b * 1024;
    const int bh = b * 4 + h;

    // Q as B-operand: lane holds Q[q=l31][dk*16 + hi*8 + z]  (Q pre-scaled)
    bf16x8 qf[4];
    int qg0 = qt * 64 + w * 32 + l31;
#pragma unroll
    for (int dk = 0; dk < 4; ++dk)
        qf[dk] = ldb8(qkv + (bb + qg0) * 768 + h * 192 + dk * 16 + hi * 8);

    // swizzled-read column granules (content granule c -> LDS granule c^x7)
    int colB[4];
#pragma unroll
    for (int c = 0; c < 4; ++c) colB[c] = ((2 * c + hi) ^ x7) * 8;

    // staging sources (pre-swizzled global addresses; row&7 invariant across i)
    int srow = w * 32 + (l >> 3);            // lds row this lane fills (i=0)
    int gsw  = (l & 7) ^ (srow & 7);
    const unsigned short* ksrc = qkv + (bb + srow) * 768 + h * 192 + 64 + gsw * 8;
    const unsigned short* vsrc = vT + ((size_t)bh * 64 + srow) * 1024 + gsw * 8;

    float mrow = -1e30f, lrow = 0.0f;
    f32x16 oacc0 = {}, oacc1 = {};

    for (int jt = 0; jt < 1024; jt += 64) {
        __syncthreads();
#pragma unroll
        for (int i = 0; i < 4; ++i) {
            gload16(ksrc + (size_t)i * 8 * 768, (char*)Kl + (w * 32 + i * 8) * 128);
            gload16(vsrc + (size_t)i * 8 * 1024, (char*)Vl + (w * 32 + i * 8) * 128);
        }
        __syncthreads();

        // S^T = K Q^T : lane holds col q=l31, rows j=(r&3)+8*(r>>2)+4*hi (+32*jn)
        f32x16 st0 = {}, st1 = {};
#pragma unroll
        for (int dk = 0; dk < 4; ++dk) {
            bf16x8 k0 = ldb8(&Kl[(l31) * 64 + colB[dk]]);
            bf16x8 k1 = ldb8(&Kl[(32 + l31) * 64 + colB[dk]]);
            st0 = MFMA32(k0, qf[dk], st0);
            st1 = MFMA32(k1, qf[dk], st1);
        }

        // row max over all 64 j: 31 local + 1 half-swap
        float pm = st0[0];
#pragma unroll
        for (int r = 1; r < 16; ++r) pm = fmaxf(pm, st0[r]);
#pragma unroll
        for (int r = 0; r < 16; ++r) pm = fmaxf(pm, st1[r]);
        pm = fmaxf(pm, __shfl_xor(pm, 32));

        // defer-max (T13): only rescale when some row grew > 8 (exp2 domain)
        if (!__all(pm - mrow <= 8.0f)) {
            float mn = fmaxf(mrow, pm);
            float ef = __builtin_amdgcn_exp2f(mrow - mn);
            mrow = mn;
            lrow *= ef;
#pragma unroll
            for (int r = 0; r < 16; ++r) {
                int qr = (r & 3) + 8 * (r >> 2) + hi * 4;
                float efq = __shfl(ef, qr);
                oacc0[r] *= efq;
                oacc1[r] *= efq;
            }
        }

        // P = exp2(S - m); row sum
        float rs = 0.0f;
#pragma unroll
        for (int r = 0; r < 16; ++r) { st0[r] = __builtin_amdgcn_exp2f(st0[r] - mrow); rs += st0[r]; }
#pragma unroll
        for (int r = 0; r < 16; ++r) { st1[r] = __builtin_amdgcn_exp2f(st1[r] - mrow); rs += st1[r]; }
        rs += __shfl_xor(rs, 32);
        lrow += rs;

        // pack P into A-fragments (in-register, no LDS)
        bf16x8 pf0, pf1, pf2, pf3;
        PACKJK(st0, 0, pf0);
        PACKJK(st0, 8, pf1);
        PACKJK(st1, 0, pf2);
        PACKJK(st1, 8, pf3);

        // O += P V : lane holds col d=l31 (+32*dn), rows q
#pragma unroll
        for (int jk = 0; jk < 4; ++jk) {
            bf16x8 pfk = (jk == 0) ? pf0 : (jk == 1) ? pf1 : (jk == 2) ? pf2 : pf3;
            bf16x8 v0 = ldb8(&Vl[(l31) * 64 + colB[jk]]);
            bf16x8 v1 = ldb8(&Vl[(32 + l31) * 64 + colB[jk]]);
            oacc0 = MFMA32(pfk, v0, oacc0);
            oacc1 = MFMA32(pfk, v1, oacc1);
        }

        ksrc += (size_t)64 * 768;
        vsrc += 64;
    }

    // epilogue: O[q][d] /= l[q]; store bf16 to ao[b][s][h*64+d]
    float rcp = 1.0f / lrow;
#pragma unroll
    for (int r = 0; r < 16; ++r) {
        int qr = (r & 3) + 8 * (r >> 2) + hi * 4;
        float lq = __shfl(rcp, qr);
        int qg = qt * 64 + w * 32 + qr;
        size_t o = (bb + qg) * 256 + h * 64 + l31;
        ao[o]      = f2bf(oacc0[r] * lq);
        ao[o + 32] = f2bf(oacc1[r] * lq);
    }
}

// ---------------- out GEMM 64x64 tiles + bias + residual, transposed fp32 store ----------------
__global__ __launch_bounds__(256) void k_gemm_out(const unsigned short* __restrict__ aoin,
                                                  const unsigned short* __restrict__ wT,
                                                  const float* __restrict__ bias,
                                                  const float* __restrict__ x,
                                                  float* __restrict__ out) {
    int bid = blockIdx.x;            // 256 mtiles * 4 ntiles
    int mt = bid >> 2, nt = bid & 3;
    int tid = threadIdx.x;
    int w = tid >> 6, l = tid & 63;
    int l15 = l & 15, lg = l >> 4;
    int wm = (w >> 1) * 32, wn = (w & 1) * 32;

    __shared__ __align__(16) unsigned short Al[64 * 32];
    __shared__ __align__(16) unsigned short Bl[64 * 32];

    f32x4 acc[2][2] = {};

    const char* Agb = (const char*)aoin + (size_t)mt * 64 * 512;
    const char* Bgb = (const char*)wT + (size_t)nt * 64 * 512;
    int r0 = w * 16;
    size_t lrow_off = (size_t)(r0 + (l >> 2)) * 512 + (l & 3) * 16;

    for (int kt = 0; kt < 256; kt += 32) {
        __syncthreads();
        gload16(Agb + lrow_off + kt * 2, (char*)Al + r0 * 64);
        gload16(Bgb + lrow_off + kt * 2, (char*)Bl + r0 * 64);
        __syncthreads();
        bf16x8 af[2], bfr[2];
#pragma unroll
        for (int mi = 0; mi < 2; ++mi)
            af[mi] = ldb8(&Al[(wm + mi * 16 + l15) * 32 + lg * 8]);
#pragma unroll
        for (int ni = 0; ni < 2; ++ni)
            bfr[ni] = ldb8(&Bl[(wn + ni * 16 + l15) * 32 + lg * 8]);
#pragma unroll
        for (int mi = 0; mi < 2; ++mi)
#pragma unroll
            for (int ni = 0; ni < 2; ++ni)
                acc[mi][ni] = MFMA16(af[mi], bfr[ni], acc[mi][ni]);
    }

#pragma unroll
    for (int ni = 0; ni < 2; ++ni) {
        int n = nt * 64 + wn + ni * 16 + l15;
        float bz = bias[n];
#pragma unroll
        for (int mi = 0; mi < 2; ++mi) {
            int mg = mt * 64 + wm + mi * 16 + lg * 4;
            int bI = mg >> 10, i = mg & 1023;
            size_t o = (((size_t)(bI * 256 + n)) << 10) + i;
            float4 xr = *reinterpret_cast<const float4*>(x + o);
            float4 res;
            res.x = acc[mi][ni][0] + bz + xr.x;
            res.y = acc[mi][ni][1] + bz + xr.y;
            res.z = acc[mi][ni][2] + bz + xr.z;
            res.w = acc[mi][ni][3] + bz + xr.w;
            *reinterpret_cast<float4*>(out + o) = res;
        }
    }
}

extern "C" void kernel_launch(void* const* d_in, const int* in_sizes, int n_in,
                              void* d_out, int out_size, void* d_ws, size_t ws_size,
                              hipStream_t stream) {
    const float* x      = (const float*)d_in[0];
    const float* w_proj = (const float*)d_in[1];
    const float* b_proj = (const float*)d_in[2];
    const float* w_out  = (const float*)d_in[3];
    const float* b_out  = (const float*)d_in[4];
    float* out = (float*)d_out;

    char* ws = (char*)d_ws;
    unsigned short* xT     = (unsigned short*)(ws);                 //  8,388,608 B (reused as vT)
    unsigned short* wprojT = (unsigned short*)(ws + 8388608);       //    393,216 B
    unsigned short* woutT  = (unsigned short*)(ws + 8781824);       //    131,072 B
    unsigned short* qkv    = (unsigned short*)(ws + 8912896);       // 25,165,824 B
    unsigned short* ao     = (unsigned short*)(ws + 34078720);      //  8,388,608 B
    unsigned short* vT     = xT;     // xT is dead after k_gemm_qkv

    k_tall<<<1088, 256, 0, stream>>>(x, w_proj, w_out, xT, wprojT, woutT);
    k_gemm_qkv<<<768, 256, 0, stream>>>(xT, wprojT, b_proj, qkv);
    k_vt<<<1024, 256, 0, stream>>>(qkv, vT);
    k_attn<<<1024, 128, 0, stream>>>(qkv, vT, ao);
    k_gemm_out<<<1024, 256, 0, stream>>>(ao, woutT, b_out, x, out);
}

// Round 9
// 137.172 us; speedup vs baseline: 1.2859x; 1.0700x over previous
//
#include <hip/hip_runtime.h>
#include <hip/hip_bf16.h>
#include <stdint.h>

// Problem: B=16, C=256, H=W=32 -> S=1024, NH=4, DK=64, N_qkv=768
typedef float f32x4 __attribute__((ext_vector_type(4)));
typedef float f32x16 __attribute__((ext_vector_type(16)));
typedef __bf16 bf16x8 __attribute__((ext_vector_type(8)));
typedef unsigned short u16x8 __attribute__((ext_vector_type(8)));
typedef int i32x4 __attribute__((ext_vector_type(4)));

#define MFMA16(a, b, c) __builtin_amdgcn_mfma_f32_16x16x32_bf16(a, b, c, 0, 0, 0)
#define MFMA32(a, b, c) __builtin_amdgcn_mfma_f32_32x32x16_bf16(a, b, c, 0, 0, 0)

// SCALE * log2(e): folded into Q so softmax runs in exp2 domain.
#define QSCALE 0.18033688011112042f

static __device__ __forceinline__ unsigned short f2bf(float f) {
    uint32_t u = __builtin_bit_cast(uint32_t, f);
    u = u + 0x7FFFu + ((u >> 16) & 1u);
    return (unsigned short)(u >> 16);
}

static __device__ __forceinline__ bf16x8 ldb8(const unsigned short* p) {
    return __builtin_bit_cast(bf16x8, *reinterpret_cast<const u16x8*>(p));
}

// async global->LDS, 16B/lane; LDS dest = wave-uniform base + lane*16
static __device__ __forceinline__ void gload16(const void* g, void* l) {
    __builtin_amdgcn_global_load_lds(
        (const __attribute__((address_space(1))) void*)g,
        (__attribute__((address_space(3))) void*)l,
        16, 0, 0);
}

// ---------------- merged transposes: fp32 [b][R][Cc] -> bf16 [b][Cc][R] ----------------
__global__ __launch_bounds__(256) void k_tall(const float* __restrict__ x,
                                              const float* __restrict__ wp,
                                              const float* __restrict__ wo,
                                              unsigned short* __restrict__ xT,
                                              unsigned short* __restrict__ wpT,
                                              unsigned short* __restrict__ woT) {
    int bid = blockIdx.x;
    const float* src; unsigned short* dst; int Cc, nCT; int lb;
    if (bid < 1024)      { src = x;  dst = xT;  Cc = 1024; nCT = 16; lb = bid; }
    else if (bid < 1072) { src = wp; dst = wpT; Cc = 768;  nCT = 12; lb = bid - 1024; }
    else                 { src = wo; dst = woT; Cc = 256;  nCT = 4;  lb = bid - 1072; }
    int R = 256, nRT = 4;
    int ct = lb % nCT;
    int rt = (lb / nCT) % nRT;
    int b  = lb / (nCT * nRT);
    int t = threadIdx.x;
    __shared__ __align__(16) unsigned short tile[64][72];
    int tr = t >> 2, tc = (t & 3) * 16;
    const float* sp = src + ((size_t)(b * R + rt * 64 + tr)) * Cc + ct * 64 + tc;
#pragma unroll
    for (int j = 0; j < 4; ++j) {
        float4 v = reinterpret_cast<const float4*>(sp)[j];
        ushort4 hv; hv.x = f2bf(v.x); hv.y = f2bf(v.y); hv.z = f2bf(v.z); hv.w = f2bf(v.w);
        *reinterpret_cast<ushort4*>(&tile[tr][tc + 4 * j]) = hv;
    }
    __syncthreads();
    int c = t >> 2, rs = (t & 3) * 16;
    u16x8 o0, o1;
#pragma unroll
    for (int z = 0; z < 8; ++z) o0[z] = tile[rs + z][c];
#pragma unroll
    for (int z = 0; z < 8; ++z) o1[z] = tile[rs + 8 + z][c];
    unsigned short* dp = dst + ((size_t)b * Cc + ct * 64 + c) * R + rt * 64 + rs;
    *reinterpret_cast<u16x8*>(dp) = o0;
    *reinterpret_cast<u16x8*>(dp + 8) = o1;
}

// ---------------- QKV GEMM: Q,K -> qkv[m][768]; V -> vT[bh][d][s] directly ----------------
__global__ __launch_bounds__(256) void k_gemm_qkv(const unsigned short* __restrict__ xT,
                                                  const unsigned short* __restrict__ wT,
                                                  const float* __restrict__ bias,
                                                  unsigned short* __restrict__ qkv,
                                                  unsigned short* __restrict__ vT) {
    int bid = blockIdx.x;            // 128 mtiles * 6 ntiles
    int mt = bid / 6, nt = bid - mt * 6;
    int tid = threadIdx.x;
    int w = tid >> 6, l = tid & 63;
    int l15 = l & 15, lg = l >> 4;
    int wm = (w >> 1) * 64, wn = (w & 1) * 64;

    __shared__ __align__(16) unsigned short Al[128 * 32];
    __shared__ __align__(16) unsigned short Bl[128 * 32];

    f32x4 acc[4][4] = {};

    const char* Agb = (const char*)xT + (size_t)mt * 128 * 512;
    const char* Bgb = (const char*)wT + (size_t)nt * 128 * 512;
    int r0 = w * 32;
    size_t lrow_off = (size_t)(r0 + (l >> 2)) * 512 + (l & 3) * 16;

    for (int kt = 0; kt < 256; kt += 32) {
        __syncthreads();
        const char* ag = Agb + lrow_off + kt * 2;
        const char* bg = Bgb + lrow_off + kt * 2;
        gload16(ag,             (char*)Al + r0 * 64);
        gload16(ag + 16 * 512,  (char*)Al + r0 * 64 + 1024);
        gload16(bg,             (char*)Bl + r0 * 64);
        gload16(bg + 16 * 512,  (char*)Bl + r0 * 64 + 1024);
        __syncthreads();
        bf16x8 af[4], bfr[4];
#pragma unroll
        for (int mi = 0; mi < 4; ++mi)
            af[mi] = ldb8(&Al[(wm + mi * 16 + l15) * 32 + lg * 8]);
#pragma unroll
        for (int ni = 0; ni < 4; ++ni)
            bfr[ni] = ldb8(&Bl[(wn + ni * 16 + l15) * 32 + lg * 8]);
#pragma unroll
        for (int mi = 0; mi < 4; ++mi)
#pragma unroll
            for (int ni = 0; ni < 4; ++ni)
                acc[mi][ni] = MFMA16(af[mi], bfr[ni], acc[mi][ni]);
    }

#pragma unroll
    for (int ni = 0; ni < 4; ++ni) {
        int n0 = nt * 128 + wn + ni * 16;      // wave-uniform; 16-strips never straddle components
        int n  = n0 + l15;
        int c0 = n0 % 192;
        float bz = bias[n];
        if (c0 >= 128) {
            // V column: write transposed, contiguous ushort4 along s
            int hq = n / 192;
            int d  = (n % 192) - 128;
#pragma unroll
            for (int mi = 0; mi < 4; ++mi) {
                int mg = mt * 128 + wm + mi * 16 + lg * 4;
                int bI = mg >> 10, s = mg & 1023;
                ushort4 hv;
                hv.x = f2bf(acc[mi][ni][0] + bz);
                hv.y = f2bf(acc[mi][ni][1] + bz);
                hv.z = f2bf(acc[mi][ni][2] + bz);
                hv.w = f2bf(acc[mi][ni][3] + bz);
                *reinterpret_cast<ushort4*>(vT + ((size_t)(bI * 4 + hq) * 64 + d) * 1024 + s) = hv;
            }
        } else {
            float qs = (c0 < 64) ? QSCALE : 1.0f;   // scale Q columns (incl. bias)
#pragma unroll
            for (int mi = 0; mi < 4; ++mi) {
                int mg = mt * 128 + wm + mi * 16 + lg * 4;
                unsigned short* qp = qkv + (size_t)mg * 768 + n;
#pragma unroll
                for (int r = 0; r < 4; ++r)
                    qp[(size_t)r * 768] = f2bf((acc[mi][ni][r] + bz) * qs);
            }
        }
    }
}

// Pack 8 exp'd P-values (j-group) into an A-fragment (4 u32) with the
// cross-half exchange (T12 pattern).
#define PACKJK(SV, R, OUT) do { \
    int pa_, pb_, pc_, pd_; \
    asm("v_cvt_pk_bf16_f32 %0, %1, %2" : "=v"(pa_) : "v"(SV[R + 0]), "v"(SV[R + 1])); \
    asm("v_cvt_pk_bf16_f32 %0, %1, %2" : "=v"(pb_) : "v"(SV[R + 2]), "v"(SV[R + 3])); \
    asm("v_cvt_pk_bf16_f32 %0, %1, %2" : "=v"(pc_) : "v"(SV[R + 4]), "v"(SV[R + 5])); \
    asm("v_cvt_pk_bf16_f32 %0, %1, %2" : "=v"(pd_) : "v"(SV[R + 6]), "v"(SV[R + 7])); \
    int pu_ = hi ? pa_ : pc_;  int psu_ = __shfl_xor(pu_, 32); \
    int pv_ = hi ? pb_ : pd_;  int psv_ = __shfl_xor(pv_, 32); \
    i32x4 pri_ = { hi ? psu_ : pa_, hi ? psv_ : pb_, hi ? pc_ : psu_, hi ? pd_ : psv_ }; \
    OUT = __builtin_bit_cast(bf16x8, pri_); \
} while (0)

// ---------------- flash attention (R6-verbatim): 2 waves x 32 q-rows, single-buffer ----------------
__global__ __launch_bounds__(128) void k_attn(const unsigned short* __restrict__ qkv,
                                              const unsigned short* __restrict__ vT,
                                              unsigned short* __restrict__ ao) {
    int bid = blockIdx.x;            // b(16) * h(4) * qt(16) = 1024
    int qt = bid & 15;
    int h  = (bid >> 4) & 3;
    int b  = bid >> 6;
    int tid = threadIdx.x;
    int w = tid >> 6;                // wave 0/1
    int l = tid & 63;
    int l31 = l & 31;
    int hi = l >> 5;                 // half-wave
    int x7 = l & 7;

    __shared__ __align__(16) unsigned short Kl[64 * 64];
    __shared__ __align__(16) unsigned short Vl[64 * 64];

    const size_t bb = (size_t)b * 1024;
    const int bh = b * 4 + h;

    // Q as B-operand: lane holds Q[q=l31][dk*16 + hi*8 + z]  (Q pre-scaled)
    bf16x8 qf[4];
    int qg0 = qt * 64 + w * 32 + l31;
#pragma unroll
    for (int dk = 0; dk < 4; ++dk)
        qf[dk] = ldb8(qkv + (bb + qg0) * 768 + h * 192 + dk * 16 + hi * 8);

    // swizzled-read column granules (content granule c -> LDS granule c^x7)
    int colB[4];
#pragma unroll
    for (int c = 0; c < 4; ++c) colB[c] = ((2 * c + hi) ^ x7) * 8;

    // staging sources (pre-swizzled global addresses; row&7 invariant across i)
    int srow = w * 32 + (l >> 3);            // lds row this lane fills (i=0)
    int gsw  = (l & 7) ^ (srow & 7);
    const unsigned short* ksrc = qkv + (bb + srow) * 768 + h * 192 + 64 + gsw * 8;
    const unsigned short* vsrc = vT + ((size_t)bh * 64 + srow) * 1024 + gsw * 8;

    float mrow = -1e30f, lrow = 0.0f;
    f32x16 oacc0 = {}, oacc1 = {};

    for (int jt = 0; jt < 1024; jt += 64) {
        __syncthreads();
#pragma unroll
        for (int i = 0; i < 4; ++i) {
            gload16(ksrc + (size_t)i * 8 * 768, (char*)Kl + (w * 32 + i * 8) * 128);
            gload16(vsrc + (size_t)i * 8 * 1024, (char*)Vl + (w * 32 + i * 8) * 128);
        }
        __syncthreads();

        // S^T = K Q^T : lane holds col q=l31, rows j=(r&3)+8*(r>>2)+4*hi (+32*jn)
        f32x16 st0 = {}, st1 = {};
#pragma unroll
        for (int dk = 0; dk < 4; ++dk) {
            bf16x8 k0 = ldb8(&Kl[(l31) * 64 + colB[dk]]);
            bf16x8 k1 = ldb8(&Kl[(32 + l31) * 64 + colB[dk]]);
            st0 = MFMA32(k0, qf[dk], st0);
            st1 = MFMA32(k1, qf[dk], st1);
        }

        // row max over all 64 j: 31 local + 1 half-swap
        float pm = st0[0];
#pragma unroll
        for (int r = 1; r < 16; ++r) pm = fmaxf(pm, st0[r]);
#pragma unroll
        for (int r = 0; r < 16; ++r) pm = fmaxf(pm, st1[r]);
        pm = fmaxf(pm, __shfl_xor(pm, 32));

        // defer-max (T13): only rescale when some row grew > 8 (exp2 domain)
        if (!__all(pm - mrow <= 8.0f)) {
            float mn = fmaxf(mrow, pm);
            float ef = __builtin_amdgcn_exp2f(mrow - mn);
            mrow = mn;
            lrow *= ef;
#pragma unroll
            for (int r = 0; r < 16; ++r) {
                int qr = (r & 3) + 8 * (r >> 2) + hi * 4;
                float efq = __shfl(ef, qr);
                oacc0[r] *= efq;
                oacc1[r] *= efq;
            }
        }

        // P = exp2(S - m); row sum
        float rs = 0.0f;
#pragma unroll
        for (int r = 0; r < 16; ++r) { st0[r] = __builtin_amdgcn_exp2f(st0[r] - mrow); rs += st0[r]; }
#pragma unroll
        for (int r = 0; r < 16; ++r) { st1[r] = __builtin_amdgcn_exp2f(st1[r] - mrow); rs += st1[r]; }
        rs += __shfl_xor(rs, 32);
        lrow += rs;

        // pack P into A-fragments (in-register, no LDS)
        bf16x8 pf0, pf1, pf2, pf3;
        PACKJK(st0, 0, pf0);
        PACKJK(st0, 8, pf1);
        PACKJK(st1, 0, pf2);
        PACKJK(st1, 8, pf3);

        // O += P V : lane holds col d=l31 (+32*dn), rows q
#pragma unroll
        for (int jk = 0; jk < 4; ++jk) {
            bf16x8 pfk = (jk == 0) ? pf0 : (jk == 1) ? pf1 : (jk == 2) ? pf2 : pf3;
            bf16x8 v0 = ldb8(&Vl[(l31) * 64 + colB[jk]]);
            bf16x8 v1 = ldb8(&Vl[(32 + l31) * 64 + colB[jk]]);
            oacc0 = MFMA32(pfk, v0, oacc0);
            oacc1 = MFMA32(pfk, v1, oacc1);
        }

        ksrc += (size_t)64 * 768;
        vsrc += 64;
    }

    // epilogue: O[q][d] /= l[q]; store bf16 to ao[b][s][h*64+d]
    float rcp = 1.0f / lrow;
#pragma unroll
    for (int r = 0; r < 16; ++r) {
        int qr = (r & 3) + 8 * (r >> 2) + hi * 4;
        float lq = __shfl(rcp, qr);
        int qg = qt * 64 + w * 32 + qr;
        size_t o = (bb + qg) * 256 + h * 64 + l31;
        ao[o]      = f2bf(oacc0[r] * lq);
        ao[o + 32] = f2bf(oacc1[r] * lq);
    }
}

// ---------------- out GEMM 128x128 tiles + bias + residual, transposed fp32 store ----------------
__global__ __launch_bounds__(256) void k_gemm_out(const unsigned short* __restrict__ aoin,
                                                  const unsigned short* __restrict__ wT,
                                                  const float* __restrict__ bias,
                                                  const float* __restrict__ x,
                                                  float* __restrict__ out) {
    int bid = blockIdx.x;            // 128 mtiles * 2 ntiles
    int mt = bid >> 1, nt = bid & 1;
    int tid = threadIdx.x;
    int w = tid >> 6, l = tid & 63;
    int l15 = l & 15, lg = l >> 4;
    int wm = (w >> 1) * 64, wn = (w & 1) * 64;

    __shared__ __align__(16) unsigned short Al[128 * 32];
    __shared__ __align__(16) unsigned short Bl[128 * 32];

    f32x4 acc[4][4] = {};

    const char* Agb = (const char*)aoin + (size_t)mt * 128 * 512;
    const char* Bgb = (const char*)wT + (size_t)nt * 128 * 512;
    int r0 = w * 32;
    size_t lrow_off = (size_t)(r0 + (l >> 2)) * 512 + (l & 3) * 16;

    for (int kt = 0; kt < 256; kt += 32) {
        __syncthreads();
        const char* ag = Agb + lrow_off + kt * 2;
        const char* bg = Bgb + lrow_off + kt * 2;
        gload16(ag,             (char*)Al + r0 * 64);
        gload16(ag + 16 * 512,  (char*)Al + r0 * 64 + 1024);
        gload16(bg,             (char*)Bl + r0 * 64);
        gload16(bg + 16 * 512,  (char*)Bl + r0 * 64 + 1024);
        __syncthreads();
        bf16x8 af[4], bfr[4];
#pragma unroll
        for (int mi = 0; mi < 4; ++mi)
            af[mi] = ldb8(&Al[(wm + mi * 16 + l15) * 32 + lg * 8]);
#pragma unroll
        for (int ni = 0; ni < 4; ++ni)
            bfr[ni] = ldb8(&Bl[(wn + ni * 16 + l15) * 32 + lg * 8]);
#pragma unroll
        for (int mi = 0; mi < 4; ++mi)
#pragma unroll
            for (int ni = 0; ni < 4; ++ni)
                acc[mi][ni] = MFMA16(af[mi], bfr[ni], acc[mi][ni]);
    }

    // out[b][n][i] = acc + bias[n] + x[b][n][i]
#pragma unroll
    for (int ni = 0; ni < 4; ++ni) {
        int n = nt * 128 + wn + ni * 16 + l15;
        float bz = bias[n];
#pragma unroll
        for (int mi = 0; mi < 4; ++mi) {
            int mg = mt * 128 + wm + mi * 16 + lg * 4;
            int bI = mg >> 10, i = mg & 1023;
            size_t o = (((size_t)(bI * 256 + n)) << 10) + i;
            float4 xr = *reinterpret_cast<const float4*>(x + o);
            float4 res;
            res.x = acc[mi][ni][0] + bz + xr.x;
            res.y = acc[mi][ni][1] + bz + xr.y;
            res.z = acc[mi][ni][2] + bz + xr.z;
            res.w = acc[mi][ni][3] + bz + xr.w;
            *reinterpret_cast<float4*>(out + o) = res;
        }
    }
}

extern "C" void kernel_launch(void* const* d_in, const int* in_sizes, int n_in,
                              void* d_out, int out_size, void* d_ws, size_t ws_size,
                              hipStream_t stream) {
    const float* x      = (const float*)d_in[0];
    const float* w_proj = (const float*)d_in[1];
    const float* b_proj = (const float*)d_in[2];
    const float* w_out  = (const float*)d_in[3];
    const float* b_out  = (const float*)d_in[4];
    float* out = (float*)d_out;

    char* ws = (char*)d_ws;
    unsigned short* xT     = (unsigned short*)(ws);                 //  8,388,608 B
    unsigned short* wprojT = (unsigned short*)(ws + 8388608);       //    393,216 B
    unsigned short* woutT  = (unsigned short*)(ws + 8781824);       //    131,072 B
    unsigned short* qkv    = (unsigned short*)(ws + 8912896);       // 25,165,824 B (V region unused)
    unsigned short* ao     = (unsigned short*)(ws + 34078720);      //  8,388,608 B
    unsigned short* vT     = (unsigned short*)(ws + 42467328);      //  8,388,608 B (separate: xT still live)
    // total 50,855,936 B

    k_tall<<<1088, 256, 0, stream>>>(x, w_proj, w_out, xT, wprojT, woutT);
    k_gemm_qkv<<<768, 256, 0, stream>>>(xT, wprojT, b_proj, qkv, vT);
    k_attn<<<1024, 128, 0, stream>>>(qkv, vT, ao);
    k_gemm_out<<<256, 256, 0, stream>>>(ao, woutT, b_out, x, out);
}